// Round 1
// baseline (1533.583 us; speedup 1.0000x reference)
//
#include <hip/hip_runtime.h>

// HGNN layer, B=4, N=E=4096, D=128, fp32 in/out, bf16 MFMA internally.

typedef __bf16 bf16;
typedef bf16 bf16x8 __attribute__((ext_vector_type(8)));
typedef float f32x4 __attribute__((ext_vector_type(4)));

#define LDP 40  // padded LDS row length (bf16 elems): 80B stride, 16B-aligned, spreads banks

union BPack { bf16 h[2]; unsigned int u; };

static __device__ __forceinline__ bf16 tob(float f) { return (bf16)f; }

// ---------------------------------------------------------------------------
// K1: x_w = x @ mlp_W + mlp_b.   x: [B*N,128] flat, W: [128,128], out same shape.
// 512 blocks x 256 threads, each block does 32 rows; W staged in 32-row chunks.
__global__ __launch_bounds__(256) void mlp_k(const float* __restrict__ x,
                                             const float* __restrict__ W,
                                             const float* __restrict__ bias,
                                             float* __restrict__ xw) {
    __shared__ float Ws[32][128];
    __shared__ float xs[32][128];
    const int t = threadIdx.x;
    const long r0 = (long)blockIdx.x * 32;

    for (int i = t * 4; i < 4096; i += 1024)
        *(float4*)&xs[i >> 7][i & 127] = *(const float4*)&x[r0 * 128 + i];

    const int d = t & 127;
    const int rg = (t >> 7) * 16;
    float acc[16];
#pragma unroll
    for (int r = 0; r < 16; ++r) acc[r] = 0.f;

    for (int kk = 0; kk < 128; kk += 32) {
        __syncthreads();
        for (int i = t * 4; i < 4096; i += 1024)
            *(float4*)&Ws[i >> 7][i & 127] =
                *(const float4*)&W[(kk + (i >> 7)) * 128 + (i & 127)];
        __syncthreads();
        for (int k = 0; k < 32; ++k) {
            float w = Ws[k][d];
#pragma unroll
            for (int r = 0; r < 16; ++r) acc[r] += xs[rg + r][kk + k] * w;
        }
    }
    const float bd = bias[d];
#pragma unroll
    for (int r = 0; r < 16; ++r)
        xw[(r0 + rg + r) * 128 + d] = acc[r] + bd;
}

// ---------------------------------------------------------------------------
// Kxt: xt[r] = dot(x[r,:], theta).  grid = B*N blocks of 1 wave.
__global__ void xtheta_k(const float* __restrict__ x, const float* __restrict__ th,
                         float* __restrict__ xt) {
    const long r = blockIdx.x;
    const int t = threadIdx.x;  // 0..63
    float p = x[r * 128 + t] * th[t] + x[r * 128 + 64 + t] * th[64 + t];
#pragma unroll
    for (int o = 32; o > 0; o >>= 1) p += __shfl_down(p, o);
    if (t == 0) xt[r] = p;
}

// ---------------------------------------------------------------------------
// K2: ht_xt[b,e] = sum_n incident[b,n,e] * xt[b,n].  grid (64 e-tiles, 4 b).
__global__ __launch_bounds__(256) void htxt_k(const float* __restrict__ inc,
                                              const float* __restrict__ xt,
                                              float* __restrict__ out) {
    const int t = threadIdx.x;
    const int e0 = blockIdx.x * 64, b = blockIdx.y;
    const int el = t & 63, ns = t >> 6;
    const float* ib = inc + ((long)b << 24);
    const float* xb = xt + b * 4096;
    float acc = 0.f;
    for (int n = ns; n < 4096; n += 4)
        acc += ib[(long)n * 4096 + e0 + el] * xb[n];
    __shared__ float s[4][64];
    s[ns][el] = acc;
    __syncthreads();
    if (t < 64)
        out[b * 4096 + e0 + t] = s[0][t] + s[1][t] + s[2][t] + s[3][t];
}

// ---------------------------------------------------------------------------
// K3: masked softmax over E per batch. attn[e] = mask ? exp(s-m)/Z : 0.
__global__ void softmax_k(const float* __restrict__ s, const int* __restrict__ mask,
                          float* __restrict__ attn) {
    const int b = blockIdx.x, t = threadIdx.x;
    __shared__ float red[1024];
    const float* sb = s + b * 4096;
    const int* mb = mask + b * 4096;

    float mx = -1e30f;
    for (int e = t; e < 4096; e += 1024)
        if (mb[e] != 0) mx = fmaxf(mx, sb[e]);
    red[t] = mx;
    __syncthreads();
    for (int st = 512; st > 0; st >>= 1) {
        if (t < st) red[t] = fmaxf(red[t], red[t + st]);
        __syncthreads();
    }
    mx = red[0];
    __syncthreads();

    float sum = 0.f;
    for (int e = t; e < 4096; e += 1024)
        if (mb[e] != 0) sum += expf(sb[e] - mx);
    red[t] = sum;
    __syncthreads();
    for (int st = 512; st > 0; st >>= 1) {
        if (t < st) red[t] += red[t + st];
        __syncthreads();
    }
    sum = red[0];
    const float inv = 1.f / sum;
    for (int e = t; e < 4096; e += 1024)
        attn[b * 4096 + e] = (mb[e] != 0) ? expf(sb[e] - mx) * inv : 0.f;
}

// ---------------------------------------------------------------------------
// The workhorse GEMM: C[b] = A[b] @ Bop[b],  A: 4096x4096 fp32 (opt. transposed
// access), Bop[k][d] = (rowsc[k]) * (B[k][d] + eps*B2[k][d]),  all converted to
// bf16 during LDS staging; fp32 accumulate via v_mfma_f32_16x16x32_bf16.
// Block: 256 thr = 4 waves; tile 64 rows x 128 cols; grid (4096/64, B).
template <bool TRANSA, bool ROWSCALE, bool ADDB2, bool EPI>
__global__ __launch_bounds__(256) void gemm_hgnn(
    const float* __restrict__ A, const float* __restrict__ Bm,
    const float* __restrict__ rowsc, const float* __restrict__ B2,
    const float* __restrict__ epsp,
    const float* __restrict__ bng, const float* __restrict__ bnb,
    const float* __restrict__ bnm, const float* __restrict__ bnv,
    float* __restrict__ C) {
    __shared__ __align__(16) bf16 As[64][LDP];
    __shared__ __align__(16) bf16 Bs[128][LDP];  // stored transposed: Bs[d][k]

    const int tid = threadIdx.x;
    const int b = blockIdx.y;
    const int m0 = blockIdx.x * 64;
    const long Aoff = (long)b << 24;            // b * 4096*4096
    const long Boff = (long)b * (4096 * 128);

    const int wave = tid >> 6, lane = tid & 63;
    const int lr = lane & 15, kb = lane >> 4;

    f32x4 acc[8];
#pragma unroll
    for (int c = 0; c < 8; ++c) acc[c] = (f32x4){0.f, 0.f, 0.f, 0.f};

    const float eps_v = ADDB2 ? epsp[0] : 0.f;

    // staging decompositions
    const int ai = tid >> 2, akp = (tid & 3) * 8;     // !TRANSA: row, k-part
    const int tk = (tid & 15) * 2, tmp_ = (tid >> 4) * 4;  // TRANSA: k-pair, m-part
    const int bk = (tid & 15) * 2, bdp = (tid >> 4) * 8;   // B: k-pair, d-part

    for (int kk = 0; kk < 4096; kk += 32) {
        // ---- stage A tile -> As[m][k] (bf16) ----
        if (!TRANSA) {
            const float* g = A + Aoff + (long)(m0 + ai) * 4096 + kk + akp;
            float4 v0 = *(const float4*)g;
            float4 v1 = *(const float4*)(g + 4);
            bf16x8 p;
            p[0] = tob(v0.x); p[1] = tob(v0.y); p[2] = tob(v0.z); p[3] = tob(v0.w);
            p[4] = tob(v1.x); p[5] = tob(v1.y); p[6] = tob(v1.z); p[7] = tob(v1.w);
            *(bf16x8*)&As[ai][akp] = p;
        } else {
            // global rows are k; 16 lanes x 4 floats cover 64 contiguous m's
            const float* g0 = A + Aoff + (long)(kk + tk) * 4096 + m0 + tmp_;
            float4 v0 = *(const float4*)g0;
            float4 v1 = *(const float4*)(g0 + 4096);
            BPack p;
            p.h[0] = tob(v0.x); p.h[1] = tob(v1.x); *(unsigned int*)&As[tmp_ + 0][tk] = p.u;
            p.h[0] = tob(v0.y); p.h[1] = tob(v1.y); *(unsigned int*)&As[tmp_ + 1][tk] = p.u;
            p.h[0] = tob(v0.z); p.h[1] = tob(v1.z); *(unsigned int*)&As[tmp_ + 2][tk] = p.u;
            p.h[0] = tob(v0.w); p.h[1] = tob(v1.w); *(unsigned int*)&As[tmp_ + 3][tk] = p.u;
        }
        // ---- stage B tile -> Bs[d][k] (bf16, transposed) ----
        {
            const float* g0 = Bm + Boff + (long)(kk + bk) * 128 + bdp;
            float4 w0 = *(const float4*)g0;
            float4 w1 = *(const float4*)(g0 + 4);
            float4 w2 = *(const float4*)(g0 + 128);
            float4 w3 = *(const float4*)(g0 + 132);
            float va[8] = {w0.x, w0.y, w0.z, w0.w, w1.x, w1.y, w1.z, w1.w};
            float vb[8] = {w2.x, w2.y, w2.z, w2.w, w3.x, w3.y, w3.z, w3.w};
            if (ADDB2) {
                const float* h0 = B2 + Boff + (long)(kk + bk) * 128 + bdp;
                float4 u0 = *(const float4*)h0;
                float4 u1 = *(const float4*)(h0 + 4);
                float4 u2 = *(const float4*)(h0 + 128);
                float4 u3 = *(const float4*)(h0 + 132);
                float ua[8] = {u0.x, u0.y, u0.z, u0.w, u1.x, u1.y, u1.z, u1.w};
                float ub[8] = {u2.x, u2.y, u2.z, u2.w, u3.x, u3.y, u3.z, u3.w};
#pragma unroll
                for (int j = 0; j < 8; ++j) {
                    va[j] += eps_v * ua[j];
                    vb[j] += eps_v * ub[j];
                }
            }
            if (ROWSCALE) {
                const float s0 = rowsc[b * 4096 + kk + bk];
                const float s1 = rowsc[b * 4096 + kk + bk + 1];
#pragma unroll
                for (int j = 0; j < 8; ++j) { va[j] *= s0; vb[j] *= s1; }
            }
#pragma unroll
            for (int j = 0; j < 8; ++j) {
                BPack p;
                p.h[0] = tob(va[j]); p.h[1] = tob(vb[j]);
                *(unsigned int*)&Bs[bdp + j][bk] = p.u;
            }
        }
        __syncthreads();

        // ---- MFMA: wave computes rows [wave*16, +16), all 8 col-tiles ----
        bf16x8 af = *(const bf16x8*)&As[wave * 16 + lr][kb * 8];
#pragma unroll
        for (int c = 0; c < 8; ++c) {
            bf16x8 bfr = *(const bf16x8*)&Bs[c * 16 + lr][kb * 8];
            acc[c] = __builtin_amdgcn_mfma_f32_16x16x32_bf16(af, bfr, acc[c], 0, 0, 0);
        }
        __syncthreads();
    }

    // ---- epilogue: C/D layout col = lane&15, row = (lane>>4)*4 + i ----
    const int rb = m0 + wave * 16 + kb * 4;
#pragma unroll
    for (int c = 0; c < 8; ++c) {
        const int col = c * 16 + lr;
#pragma unroll
        for (int i = 0; i < 4; ++i) {
            float v = acc[c][i];
            if (EPI) {
                v = (v >= 0.f) ? v : 0.01f * v;                       // leaky relu
                v = (v - bnm[col]) * rsqrtf(bnv[col] + 1e-5f) * bng[col] + bnb[col];
            }
            C[Boff + (long)(rb + i) * 128 + col] = v;
        }
    }
}

// ---------------------------------------------------------------------------
extern "C" void kernel_launch(void* const* d_in, const int* in_sizes, int n_in,
                              void* d_out, int out_size, void* d_ws, size_t ws_size,
                              hipStream_t stream) {
    const float* incident = (const float*)d_in[0];  // [B,N,E]
    const float* degree_v = (const float*)d_in[1];  // [B,N,N]
    const float* degree_e = (const float*)d_in[2];  // [B,E,E]
    const float* x        = (const float*)d_in[3];  // [B,N,D]
    const int*   e_masks  = (const int*)d_in[4];    // [B,E]
    const float* mlp_W    = (const float*)d_in[5];  // [D,D]
    const float* mlp_b    = (const float*)d_in[6];  // [D]
    const float* theta    = (const float*)d_in[7];  // [D,1]
    const float* epsp     = (const float*)d_in[8];  // [1]
    const float* bng      = (const float*)d_in[9];
    const float* bnb      = (const float*)d_in[10];
    const float* bnm      = (const float*)d_in[11];
    const float* bnv      = (const float*)d_in[12];
    float* out = (float*)d_out;

    float* ws  = (float*)d_ws;
    float* xw  = ws;            // [B*N*128]  x @ W + b
    float* hxw = ws + 2097152;  // [B*E*128]  Ht @ xw
    float* t1  = ws + 4194304;  // [B*4096*128] scratch
    float* t2  = ws + 6291456;  // [B*4096*128] scratch
    float* xt  = ws + 8388608;  // [B*N]  x @ theta
    float* hxt = ws + 8404992;  // [B*E]  Ht @ xt
    float* att = ws + 8421376;  // [B*E]  softmax

    mlp_k<<<512, 256, 0, stream>>>(x, mlp_W, mlp_b, xw);
    xtheta_k<<<16384, 64, 0, stream>>>(x, theta, xt);
    htxt_k<<<dim3(64, 4), 256, 0, stream>>>(incident, xt, hxt);
    softmax_k<<<4, 1024, 0, stream>>>(hxt, e_masks, att);

    const dim3 gg(64, 4);
    // G1: ht_x_w = Ht @ xw
    gemm_hgnn<true, false, false, false><<<gg, 256, 0, stream>>>(
        incident, xw, nullptr, nullptr, nullptr, nullptr, nullptr, nullptr, nullptr, hxw);
    // G2: t1 = incident @ (attn * hxw)
    gemm_hgnn<false, true, false, false><<<gg, 256, 0, stream>>>(
        incident, hxw, att, nullptr, nullptr, nullptr, nullptr, nullptr, nullptr, t1);
    // G3: t2 = degree_v @ t1
    gemm_hgnn<false, false, false, false><<<gg, 256, 0, stream>>>(
        degree_v, t1, nullptr, nullptr, nullptr, nullptr, nullptr, nullptr, nullptr, t2);
    // G4: t1 = Ht @ t2
    gemm_hgnn<true, false, false, false><<<gg, 256, 0, stream>>>(
        incident, t2, nullptr, nullptr, nullptr, nullptr, nullptr, nullptr, nullptr, t1);
    // G5: t2 = degree_e @ t1
    gemm_hgnn<false, false, false, false><<<gg, 256, 0, stream>>>(
        degree_e, t1, nullptr, nullptr, nullptr, nullptr, nullptr, nullptr, nullptr, t2);
    // G6: out = BN(leaky(incident @ (t2 + eps*hxw)))
    gemm_hgnn<false, false, true, true><<<gg, 256, 0, stream>>>(
        incident, t2, nullptr, hxw, epsp, bng, bnb, bnm, bnv, out);
}

// Round 2
// 777.510 us; speedup vs baseline: 1.9724x; 1.9724x over previous
//
#include <hip/hip_runtime.h>

// HGNN layer, B=4, N=E=4096, D=128, fp32 in/out, bf16 MFMA internally.
// Round 2: 8-wave 64x128 tiles + split-K=2 (partials summed in next gemm's
// B-staging), hxt folded into G1 staging, LDS XOR-swizzle, coalesced staging.

typedef __bf16 bf16;
typedef bf16 bf16x8 __attribute__((ext_vector_type(8)));
typedef float f32x4 __attribute__((ext_vector_type(4)));

#define LDK 72  // LDS row stride in bf16 elems (144 B)
#define SWZ(r, c) ((c) ^ ((((r) >> 3) & 7) << 3))

union BPack { bf16 h[2]; unsigned int u; };
static __device__ __forceinline__ bf16 tob(float f) { return (bf16)f; }

// ---------------------------------------------------------------------------
// K1: x_w = x @ mlp_W + mlp_b.   x: [B*N,128] flat, W: [128,128].
__global__ __launch_bounds__(256) void mlp_k(const float* __restrict__ x,
                                             const float* __restrict__ W,
                                             const float* __restrict__ bias,
                                             float* __restrict__ xw) {
    __shared__ float Ws[32][128];
    __shared__ float xs[32][128];
    const int t = threadIdx.x;
    const long r0 = (long)blockIdx.x * 32;

    for (int i = t * 4; i < 4096; i += 1024)
        *(float4*)&xs[i >> 7][i & 127] = *(const float4*)&x[r0 * 128 + i];

    const int d = t & 127;
    const int rg = (t >> 7) * 16;
    float acc[16];
#pragma unroll
    for (int r = 0; r < 16; ++r) acc[r] = 0.f;

    for (int kk = 0; kk < 128; kk += 32) {
        __syncthreads();
        for (int i = t * 4; i < 4096; i += 1024)
            *(float4*)&Ws[i >> 7][i & 127] =
                *(const float4*)&W[(kk + (i >> 7)) * 128 + (i & 127)];
        __syncthreads();
        for (int k = 0; k < 32; ++k) {
            float w = Ws[k][d];
#pragma unroll
            for (int r = 0; r < 16; ++r) acc[r] += xs[rg + r][kk + k] * w;
        }
    }
    const float bd = bias[d];
#pragma unroll
    for (int r = 0; r < 16; ++r)
        xw[(r0 + rg + r) * 128 + d] = acc[r] + bd;
}

// ---------------------------------------------------------------------------
// xt[r] = dot(x[r,:], theta).  grid = B*N blocks of 1 wave.
__global__ void xtheta_k(const float* __restrict__ x, const float* __restrict__ th,
                         float* __restrict__ xt) {
    const long r = blockIdx.x;
    const int t = threadIdx.x;  // 0..63
    float p = x[r * 128 + t] * th[t] + x[r * 128 + 64 + t] * th[64 + t];
#pragma unroll
    for (int o = 32; o > 0; o >>= 1) p += __shfl_down(p, o);
    if (t == 0) xt[r] = p;
}

// ---------------------------------------------------------------------------
// masked softmax over E per batch; scores from ks-split hxt partials.
__global__ void softmax_k(const float* __restrict__ hp, int ks,
                          const int* __restrict__ mask, float* __restrict__ attn) {
    const int b = blockIdx.x, t = threadIdx.x;
    __shared__ float red[1024];
    const int* mb = mask + b * 4096;

    float mx = -1e30f;
    for (int e = t; e < 4096; e += 1024) {
        if (mb[e] != 0) {
            float sc = hp[b * 4096 + e] + (ks == 2 ? hp[16384 + b * 4096 + e] : 0.f);
            mx = fmaxf(mx, sc);
        }
    }
    red[t] = mx;
    __syncthreads();
    for (int st = 512; st > 0; st >>= 1) {
        if (t < st) red[t] = fmaxf(red[t], red[t + st]);
        __syncthreads();
    }
    mx = red[0];
    __syncthreads();

    float sum = 0.f;
    for (int e = t; e < 4096; e += 1024) {
        if (mb[e] != 0) {
            float sc = hp[b * 4096 + e] + (ks == 2 ? hp[16384 + b * 4096 + e] : 0.f);
            sum += expf(sc - mx);
        }
    }
    red[t] = sum;
    __syncthreads();
    for (int st = 512; st > 0; st >>= 1) {
        if (t < st) red[t] += red[t + st];
        __syncthreads();
    }
    sum = red[0];
    const float inv = 1.f / sum;
    for (int e = t; e < 4096; e += 1024) {
        float sc = hp[b * 4096 + e] + (ks == 2 ? hp[16384 + b * 4096 + e] : 0.f);
        attn[b * 4096 + e] = (mb[e] != 0) ? expf(sc - mx) * inv : 0.f;
    }
}

// ---------------------------------------------------------------------------
// GEMM: P[ksi][b] (+)= A[b][kchunk] @ Bop[b][kchunk]
//  A: 4096x4096 fp32 (TRANSA -> A accessed as [k][m]).
//  Bop[k][d] = rowsc[k] * ( (Bp0+Bp1)[k][d] + eps*(B2p0+B2p1)[k][d] )
//  CHAIN: B comes from split-K partial pair of the previous gemm.
//  HXT: also accumulate hxt[e] = sum_n A^T[e][n]*xt[n] from staging registers.
// Block: 512 thr = 8 waves; tile 64 rows x 128 cols x BK=64; grid (64, KS, 4).
template <int KS, bool TRANSA, bool CHAIN, bool ROWSCALE, bool ADDB2, bool HXT>
__global__ __launch_bounds__(512, 4) void gemm_hgnn(
    const float* __restrict__ A, const float* __restrict__ Bp,
    const float* __restrict__ rowsc, const float* __restrict__ B2p,
    const float* __restrict__ epsp, const float* __restrict__ xtv,
    float* __restrict__ Pout, float* __restrict__ hxtp) {
    __shared__ __align__(16) bf16 As[64][LDK];
    __shared__ __align__(16) bf16 Bs[128][LDK];

    const int tid = threadIdx.x;
    const int m0 = blockIdx.x * 64;
    const int ksi = blockIdx.y;
    const int b = blockIdx.z;
    constexpr int KCH = 4096 / KS;
    const int kbeg = ksi * KCH;
    const long Aoff = (long)b << 24;         // b*4096*4096
    const long Boff0 = (long)b * 524288;     // b*4096*128
    const long PSTR = 2097152;               // 4*4096*128 between ks slices

    const int wave = tid >> 6, lane = tid & 63;
    const int lr = lane & 15, kb = lane >> 4;
    const int wm = (wave >> 1) * 16, wn = (wave & 1) * 64;

    // staging decompositions
    const int ar = tid >> 3, akp = (tid & 7) * 8;       // !TRANSA: row, k-part
    const int atm = (tid & 15) * 4, akp2 = (tid >> 4) * 2;  // TRANSA: m-part, k-pair
    const int bd = (tid & 15) * 8, bk = (tid >> 4) * 2;     // B: d-part, k-pair

    const float eps_v = ADDB2 ? epsp[0] : 0.f;

    f32x4 acc[4];
#pragma unroll
    for (int c = 0; c < 4; ++c) acc[c] = (f32x4){0.f, 0.f, 0.f, 0.f};
    float hacc[4] = {0.f, 0.f, 0.f, 0.f};

    for (int kk = kbeg; kk < kbeg + KCH; kk += 64) {
        // ---- stage A tile -> As[m][k] (bf16, swizzled) ----
        if constexpr (!TRANSA) {
            const float* g = A + Aoff + (long)(m0 + ar) * 4096 + kk + akp;
            float4 v0 = *(const float4*)g;
            float4 v1 = *(const float4*)(g + 4);
            bf16x8 p;
            p[0] = tob(v0.x); p[1] = tob(v0.y); p[2] = tob(v0.z); p[3] = tob(v0.w);
            p[4] = tob(v1.x); p[5] = tob(v1.y); p[6] = tob(v1.z); p[7] = tob(v1.w);
            *(bf16x8*)&As[ar][SWZ(ar, akp)] = p;
        } else {
            const float* g0 = A + Aoff + (long)(kk + akp2) * 4096 + m0 + atm;
            float4 v0 = *(const float4*)g0;
            float4 v1 = *(const float4*)(g0 + 4096);
            float u0[4] = {v0.x, v0.y, v0.z, v0.w};
            float u1[4] = {v1.x, v1.y, v1.z, v1.w};
            if constexpr (HXT) {
                const float xv0 = xtv[b * 4096 + kk + akp2];
                const float xv1 = xtv[b * 4096 + kk + akp2 + 1];
#pragma unroll
                for (int j = 0; j < 4; ++j) hacc[j] += u0[j] * xv0 + u1[j] * xv1;
            }
#pragma unroll
            for (int j = 0; j < 4; ++j) {
                BPack p;
                p.h[0] = tob(u0[j]); p.h[1] = tob(u1[j]);
                *(unsigned int*)&As[atm + j][SWZ(atm + j, akp2)] = p.u;
            }
        }
        // ---- stage B tile -> Bs[d][k] (bf16, transposed, swizzled) ----
        {
            const float* p0 = Bp + Boff0 + (long)(kk + bk) * 128 + bd;
            float4 x0 = *(const float4*)p0;
            float4 x1 = *(const float4*)(p0 + 4);
            float4 y0 = *(const float4*)(p0 + 128);
            float4 y1 = *(const float4*)(p0 + 132);
            float va[8] = {x0.x, x0.y, x0.z, x0.w, x1.x, x1.y, x1.z, x1.w};
            float vb[8] = {y0.x, y0.y, y0.z, y0.w, y1.x, y1.y, y1.z, y1.w};
            if constexpr (CHAIN && KS == 2) {
                const float* p1 = p0 + PSTR;
                float4 c0 = *(const float4*)p1;
                float4 c1 = *(const float4*)(p1 + 4);
                float4 d0 = *(const float4*)(p1 + 128);
                float4 d1 = *(const float4*)(p1 + 132);
                float wa[8] = {c0.x, c0.y, c0.z, c0.w, c1.x, c1.y, c1.z, c1.w};
                float wb[8] = {d0.x, d0.y, d0.z, d0.w, d1.x, d1.y, d1.z, d1.w};
#pragma unroll
                for (int j = 0; j < 8; ++j) { va[j] += wa[j]; vb[j] += wb[j]; }
            }
            if constexpr (ADDB2) {
                const float* q0 = B2p + Boff0 + (long)(kk + bk) * 128 + bd;
                float4 c0 = *(const float4*)q0;
                float4 c1 = *(const float4*)(q0 + 4);
                float4 d0 = *(const float4*)(q0 + 128);
                float4 d1 = *(const float4*)(q0 + 132);
                float qa[8] = {c0.x, c0.y, c0.z, c0.w, c1.x, c1.y, c1.z, c1.w};
                float qb[8] = {d0.x, d0.y, d0.z, d0.w, d1.x, d1.y, d1.z, d1.w};
                if constexpr (KS == 2) {
                    const float* q1 = q0 + PSTR;
                    float4 e0 = *(const float4*)q1;
                    float4 e1 = *(const float4*)(q1 + 4);
                    float4 f0 = *(const float4*)(q1 + 128);
                    float4 f1 = *(const float4*)(q1 + 132);
                    float ra[8] = {e0.x, e0.y, e0.z, e0.w, e1.x, e1.y, e1.z, e1.w};
                    float rb2[8] = {f0.x, f0.y, f0.z, f0.w, f1.x, f1.y, f1.z, f1.w};
#pragma unroll
                    for (int j = 0; j < 8; ++j) { qa[j] += ra[j]; qb[j] += rb2[j]; }
                }
#pragma unroll
                for (int j = 0; j < 8; ++j) {
                    va[j] += eps_v * qa[j];
                    vb[j] += eps_v * qb[j];
                }
            }
            if constexpr (ROWSCALE) {
                const float s0 = rowsc[b * 4096 + kk + bk];
                const float s1 = rowsc[b * 4096 + kk + bk + 1];
#pragma unroll
                for (int j = 0; j < 8; ++j) { va[j] *= s0; vb[j] *= s1; }
            }
#pragma unroll
            for (int j = 0; j < 8; ++j) {
                BPack p;
                p.h[0] = tob(va[j]); p.h[1] = tob(vb[j]);
                *(unsigned int*)&Bs[bd + j][SWZ(bd + j, bk)] = p.u;
            }
        }
        __syncthreads();

        // ---- MFMA: wave owns 16 rows (wm) x 64 cols (wn) ----
        const int rA = wm + lr;
        bf16x8 af0 = *(const bf16x8*)&As[rA][SWZ(rA, kb * 8)];
        bf16x8 af1 = *(const bf16x8*)&As[rA][SWZ(rA, kb * 8 + 32)];
#pragma unroll
        for (int c = 0; c < 4; ++c) {
            const int rB = wn + c * 16 + lr;
            bf16x8 b0 = *(const bf16x8*)&Bs[rB][SWZ(rB, kb * 8)];
            acc[c] = __builtin_amdgcn_mfma_f32_16x16x32_bf16(af0, b0, acc[c], 0, 0, 0);
        }
#pragma unroll
        for (int c = 0; c < 4; ++c) {
            const int rB = wn + c * 16 + lr;
            bf16x8 b1 = *(const bf16x8*)&Bs[rB][SWZ(rB, kb * 8 + 32)];
            acc[c] = __builtin_amdgcn_mfma_f32_16x16x32_bf16(af1, b1, acc[c], 0, 0, 0);
        }
        __syncthreads();
    }

    // ---- store partials: C/D layout col = lane&15, row = (lane>>4)*4 + i ----
    float* Cp = Pout + (long)(ksi * 4 + b) * 524288;
    const int rb = m0 + wm + kb * 4;
#pragma unroll
    for (int c = 0; c < 4; ++c) {
        const int col = wn + c * 16 + lr;
#pragma unroll
        for (int i = 0; i < 4; ++i)
            Cp[(long)(rb + i) * 128 + col] = acc[c][i];
    }

    if constexpr (HXT) {
        __shared__ float hred[32][65];
#pragma unroll
        for (int j = 0; j < 4; ++j) hred[tid >> 4][atm + j] = hacc[j];
        __syncthreads();
        if (tid < 64) {
            float s = 0.f;
#pragma unroll
            for (int r = 0; r < 32; ++r) s += hred[r][tid];
            hxtp[(long)(ksi * 4 + b) * 4096 + m0 + tid] = s;
        }
    }
}

// ---------------------------------------------------------------------------
// final: out = BN(leaky_relu(p0 + p1))
__global__ __launch_bounds__(256) void reduce_epi_k(
    const float* __restrict__ P, int ks,
    const float* __restrict__ bng, const float* __restrict__ bnb,
    const float* __restrict__ bnm, const float* __restrict__ bnv,
    float* __restrict__ out) {
    const long i4 = (long)blockIdx.x * 256 + threadIdx.x;  // float4 index
    if (i4 >= 524288) return;
    float4 v = ((const float4*)P)[i4];
    if (ks == 2) {
        float4 w = ((const float4*)(P + 2097152))[i4];
        v.x += w.x; v.y += w.y; v.z += w.z; v.w += w.w;
    }
    const int col = ((int)i4 & 31) * 4;
    float4 g = *(const float4*)&bng[col];
    float4 bb = *(const float4*)&bnb[col];
    float4 m = *(const float4*)&bnm[col];
    float4 s = *(const float4*)&bnv[col];
    float r[4] = {v.x, v.y, v.z, v.w};
    float gg[4] = {g.x, g.y, g.z, g.w}, b2[4] = {bb.x, bb.y, bb.z, bb.w};
    float mm[4] = {m.x, m.y, m.z, m.w}, vv[4] = {s.x, s.y, s.z, s.w};
#pragma unroll
    for (int j = 0; j < 4; ++j) {
        float t = r[j];
        t = (t >= 0.f) ? t : 0.01f * t;
        r[j] = (t - mm[j]) * rsqrtf(vv[j] + 1e-5f) * gg[j] + b2[j];
    }
    ((float4*)out)[i4] = (float4){r[0], r[1], r[2], r[3]};
}

// ---------------------------------------------------------------------------
template <int KS>
static void run_all(const float* incident, const float* degree_v, const float* degree_e,
                    const float* x, const int* e_masks, const float* mlp_W,
                    const float* mlp_b, const float* theta, const float* epsp,
                    const float* bng, const float* bnb, const float* bnm,
                    const float* bnv, float* out, float* ws, hipStream_t stream) {
    float* xw   = ws;                       // 2M
    float* P1   = xw + 2097152;             // KS*2M  (hxw partials)
    float* PA   = P1 + (long)KS * 2097152;  // KS*2M
    float* PB   = PA + (long)KS * 2097152;  // KS*2M
    float* xt   = PB + (long)KS * 2097152;  // 16K
    float* hxtp = xt + 16384;               // KS*16K
    float* att  = hxtp + (long)KS * 16384;  // 16K

    mlp_k<<<512, 256, 0, stream>>>(x, mlp_W, mlp_b, xw);
    xtheta_k<<<16384, 64, 0, stream>>>(x, theta, xt);

    const dim3 gg(64, KS, 4);
    // G1: hxw = Ht @ xw  (+ hxt side-product)
    gemm_hgnn<KS, true, false, false, false, true><<<gg, 512, 0, stream>>>(
        incident, xw, nullptr, nullptr, nullptr, xt, P1, hxtp);
    softmax_k<<<4, 1024, 0, stream>>>(hxtp, KS, e_masks, att);
    // G2: PA = incident @ (attn * hxw)
    gemm_hgnn<KS, false, true, true, false, false><<<gg, 512, 0, stream>>>(
        incident, P1, att, nullptr, nullptr, nullptr, PA, nullptr);
    // G3: PB = degree_v @ PA
    gemm_hgnn<KS, false, true, false, false, false><<<gg, 512, 0, stream>>>(
        degree_v, PA, nullptr, nullptr, nullptr, nullptr, PB, nullptr);
    // G4: PA = Ht @ PB
    gemm_hgnn<KS, true, true, false, false, false><<<gg, 512, 0, stream>>>(
        incident, PB, nullptr, nullptr, nullptr, nullptr, PA, nullptr);
    // G5: PB = degree_e @ PA
    gemm_hgnn<KS, false, true, false, false, false><<<gg, 512, 0, stream>>>(
        degree_e, PA, nullptr, nullptr, nullptr, nullptr, PB, nullptr);
    // G6: PA = incident @ (PB + eps*hxw)
    gemm_hgnn<KS, false, true, false, true, false><<<gg, 512, 0, stream>>>(
        incident, PB, nullptr, P1, epsp, nullptr, PA, nullptr);
    // out = BN(leaky(PA summed over ks))
    reduce_epi_k<<<2048, 256, 0, stream>>>(PA, KS, bng, bnb, bnm, bnv, out);
}

extern "C" void kernel_launch(void* const* d_in, const int* in_sizes, int n_in,
                              void* d_out, int out_size, void* d_ws, size_t ws_size,
                              hipStream_t stream) {
    const float* incident = (const float*)d_in[0];
    const float* degree_v = (const float*)d_in[1];
    const float* degree_e = (const float*)d_in[2];
    const float* x        = (const float*)d_in[3];
    const int*   e_masks  = (const int*)d_in[4];
    const float* mlp_W    = (const float*)d_in[5];
    const float* mlp_b    = (const float*)d_in[6];
    const float* theta    = (const float*)d_in[7];
    const float* epsp     = (const float*)d_in[8];
    const float* bng      = (const float*)d_in[9];
    const float* bnb      = (const float*)d_in[10];
    const float* bnm      = (const float*)d_in[11];
    const float* bnv      = (const float*)d_in[12];
    float* out = (float*)d_out;
    float* ws = (float*)d_ws;

    // KS=2 needs (2M + 3*2*2M + 16K + 2*16K + 16K) floats = 58,982,400 bytes.
    const size_t need2 = 58982400ull;
    if (ws_size >= need2)
        run_all<2>(incident, degree_v, degree_e, x, e_masks, mlp_W, mlp_b, theta,
                   epsp, bng, bnb, bnm, bnv, out, ws, stream);
    else
        run_all<1>(incident, degree_v, degree_e, x, e_masks, mlp_W, mlp_b, theta,
                   epsp, bng, bnb, bnm, bnv, out, ws, stream);
}

// Round 3
// 541.014 us; speedup vs baseline: 2.8346x; 1.4371x over previous
//
#include <hip/hip_runtime.h>

// HGNN layer, B=4, N=E=4096, D=128, fp32 in/out.
// Round 3: incident (1% dense, values {0,1}) -> 64-bit bitmasks; the 4
// incident ops become deterministic bit-scan gathers (fp32-exact). Only the
// two degree GEMMs stay dense bf16-MFMA, now with depth-2 register prefetch.

typedef __bf16 bf16;
typedef bf16 bf16x8 __attribute__((ext_vector_type(8)));
typedef float f32x4 __attribute__((ext_vector_type(4)));
typedef unsigned long long u64;

#define LDK 72  // LDS row stride in bf16 elems
#define SWZ(r, c) ((c) ^ ((((r) >> 3) & 7) << 3))

union BPack { bf16 h[2]; unsigned int u; };
static __device__ __forceinline__ bf16 tob(float f) { return (bf16)f; }

// ---------------------------------------------------------------------------
// K1: x_w = x @ mlp_W + mlp_b, fused xt = x @ theta.
__global__ __launch_bounds__(256) void mlp_k(const float* __restrict__ x,
                                             const float* __restrict__ W,
                                             const float* __restrict__ bias,
                                             const float* __restrict__ theta,
                                             float* __restrict__ xw,
                                             float* __restrict__ xt) {
    __shared__ float Ws[32][128];
    __shared__ float xs[32][128];
    const int t = threadIdx.x;
    const long r0 = (long)blockIdx.x * 32;

    for (int i = t * 4; i < 4096; i += 1024)
        *(float4*)&xs[i >> 7][i & 127] = *(const float4*)&x[r0 * 128 + i];

    const int d = t & 127;
    const int rg = (t >> 7) * 16;
    float acc[16];
#pragma unroll
    for (int r = 0; r < 16; ++r) acc[r] = 0.f;

    for (int kk = 0; kk < 128; kk += 32) {
        __syncthreads();
        for (int i = t * 4; i < 4096; i += 1024)
            *(float4*)&Ws[i >> 7][i & 127] =
                *(const float4*)&W[(kk + (i >> 7)) * 128 + (i & 127)];
        __syncthreads();
        for (int k = 0; k < 32; ++k) {
            float w = Ws[k][d];
#pragma unroll
            for (int r = 0; r < 16; ++r) acc[r] += xs[rg + r][kk + k] * w;
        }
    }
    const float bd = bias[d];
#pragma unroll
    for (int r = 0; r < 16; ++r)
        xw[(r0 + rg + r) * 128 + d] = acc[r] + bd;

    if (t < 32) {
        float s = 0.f;
        for (int k = 0; k < 128; ++k) s += xs[t][k] * theta[k];
        xt[r0 + t] = s;
    }
}

// ---------------------------------------------------------------------------
// Row bitmask: rowmask[b][n][w] bit l = (incident[b][n][w*64+l] != 0).
__global__ __launch_bounds__(256) void bmask_k(const float* __restrict__ inc,
                                               u64* __restrict__ rowmask) {
    const int b = blockIdx.y;
    const int n = blockIdx.x * 4 + (threadIdx.x >> 6);
    const int l = threadIdx.x & 63;
    const float* row = inc + ((long)b << 24) + (long)n * 4096;
    u64* out = rowmask + ((long)b * 4096 + n) * 64;
    for (int w = 0; w < 64; ++w) {
        u64 m = __ballot(row[w * 64 + l] != 0.f);
        if (l == 0) out[w] = m;
    }
}

// 64x64 bit-tile transpose: colmask[b][e][w'] bit j = incident[b][w'*64+j][e].
__global__ void btrans_k(const u64* __restrict__ rowmask, u64* __restrict__ colmask) {
    const int tn = blockIdx.x, te = blockIdx.y, b = blockIdx.z;
    const int l = threadIdx.x;
    __shared__ u64 w[64];
    w[l] = rowmask[((long)b * 4096 + tn * 64 + l) * 64 + te];
    __syncthreads();
    u64 o = 0;
#pragma unroll 8
    for (int j = 0; j < 64; ++j) o |= ((w[j] >> l) & 1ull) << j;
    colmask[((long)b * 4096 + te * 64 + l) * 64 + tn] = o;
}

// ---------------------------------------------------------------------------
// masked softmax over E per batch.
__global__ void softmax_k(const float* __restrict__ sc, const int* __restrict__ mask,
                          float* __restrict__ attn) {
    const int b = blockIdx.x, t = threadIdx.x;
    __shared__ float red[1024];
    const float* sb = sc + b * 4096;
    const int* mb = mask + b * 4096;

    float mx = -1e30f;
    for (int e = t; e < 4096; e += 1024)
        if (mb[e] != 0) mx = fmaxf(mx, sb[e]);
    red[t] = mx;
    __syncthreads();
    for (int st = 512; st > 0; st >>= 1) {
        if (t < st) red[t] = fmaxf(red[t], red[t + st]);
        __syncthreads();
    }
    mx = red[0];
    __syncthreads();

    float sum = 0.f;
    for (int e = t; e < 4096; e += 1024)
        if (mb[e] != 0) sum += expf(sb[e] - mx);
    red[t] = sum;
    __syncthreads();
    for (int st = 512; st > 0; st >>= 1) {
        if (t < st) red[t] += red[t + st];
        __syncthreads();
    }
    const float inv = 1.f / red[0];
    for (int e = t; e < 4096; e += 1024)
        attn[b * 4096 + e] = (mb[e] != 0) ? expf(sb[e] - mx) * inv : 0.f;
}

// ---------------------------------------------------------------------------
// Bit-scan gather: out[r,:] = sum over set bits e of mask-row r of
//   Bval(e) = [pair-sum](src[e,:]) [+ eps*src2[e,:]] [* attn[e]]
// HXT: also hxt[r] += sum xt[e]. EPI: leaky-relu + BN on the result.
// grid (1024, 4), block 256 = 4 waves, one output row per wave.
template <int PAIR, bool SCALE, bool ADDEPS, bool HXT, bool EPI>
__global__ __launch_bounds__(256) void gather_k(
    const u64* __restrict__ mask, const float* __restrict__ src,
    const float* __restrict__ src2, const float* __restrict__ attn,
    const float* __restrict__ xt, const float* __restrict__ epsp,
    const float* __restrict__ bng, const float* __restrict__ bnb,
    const float* __restrict__ bnm, const float* __restrict__ bnv,
    float* __restrict__ out, float* __restrict__ hxt) {
    const int b = blockIdx.y;
    const int r = blockIdx.x * 4 + (threadIdx.x >> 6);
    const int l = threadIdx.x & 63;
    const u64 wrd = mask[((long)b * 4096 + r) * 64 + l];
    const float* S = src + (long)b * 524288;
    const float* S2 = ADDEPS ? (src2 + (long)b * 524288) : nullptr;
    const float eps_v = ADDEPS ? epsp[0] : 0.f;
    const int c0 = 2 * l;

    float ax = 0.f, ay = 0.f, hacc = 0.f;
    for (int wi = 0; wi < 64; ++wi) {
        u64 m = __shfl(wrd, wi);
        while (m) {
            const int bit = __builtin_ctzll(m);
            m &= m - 1;
            const int e = (wi << 6) + bit;
            const float* p = S + e * 128 + c0;
            float2 v = *(const float2*)p;
            float vx = v.x, vy = v.y;
            if (PAIR == 2) {
                float2 v2 = *(const float2*)(p + 2097152);
                vx += v2.x; vy += v2.y;
            }
            if (ADDEPS) {
                float2 u = *(const float2*)(S2 + e * 128 + c0);
                vx += eps_v * u.x; vy += eps_v * u.y;
            }
            if (SCALE) {
                const float s = attn[b * 4096 + e];
                vx *= s; vy *= s;
            }
            if (HXT) hacc += xt[b * 4096 + e];
            ax += vx; ay += vy;
        }
    }
    if (EPI) {
        float t0 = (ax >= 0.f) ? ax : 0.01f * ax;
        float t1 = (ay >= 0.f) ? ay : 0.01f * ay;
        ax = (t0 - bnm[c0]) * rsqrtf(bnv[c0] + 1e-5f) * bng[c0] + bnb[c0];
        ay = (t1 - bnm[c0 + 1]) * rsqrtf(bnv[c0 + 1] + 1e-5f) * bng[c0 + 1] + bnb[c0 + 1];
    }
    *(float2*)&out[(long)b * 524288 + (long)r * 128 + c0] = (float2){ax, ay};
    if (HXT && l == 0) hxt[b * 4096 + r] = hacc;
}

// ---------------------------------------------------------------------------
// Dense bf16-MFMA GEMM with depth-2 register prefetch:
// P[ksi][b] = A[b][:, kchunk] @ toBf16(Bsrc[b][kchunk, :]).
// Block 512 thr = 8 waves; tile 64x128, BK=64 (x2 unrolled); grid (64, KS, 4).
template <int KS>
__global__ __launch_bounds__(512, 4) void gemm_dense(
    const float* __restrict__ A, const float* __restrict__ Bsrc,
    float* __restrict__ P) {
    __shared__ __align__(16) bf16 As[64][LDK];
    __shared__ __align__(16) bf16 Bs[128][LDK];

    const int tid = threadIdx.x;
    const int m0 = blockIdx.x * 64;
    const int ksi = blockIdx.y;
    const int b = blockIdx.z;
    constexpr int KCH = 4096 / KS;
    const int kbeg = ksi * KCH, kend = kbeg + KCH;
    const long Aoff = (long)b << 24;
    const long Boff = (long)b * 524288;

    const int wave = tid >> 6, lane = tid & 63;
    const int lr = lane & 15, kb = lane >> 4;
    const int wm = (wave >> 1) * 16, wn = (wave & 1) * 64;

    const int ar = tid >> 3, akp = (tid & 7) * 8;
    const int bd = (tid & 15) * 8, bk = (tid >> 4) * 2;

    const float* Abase = A + Aoff + (long)(m0 + ar) * 4096 + akp;
    const float* Bbase = Bsrc + Boff + (long)bk * 128 + bd;

    f32x4 acc[4];
#pragma unroll
    for (int c = 0; c < 4; ++c) acc[c] = (f32x4){0.f, 0.f, 0.f, 0.f};

    float4 xa0, xa1, xb0, xb1, xb2, xb3;
    float4 ya0, ya1, yb0, yb1, yb2, yb3;

#define GLOAD(kk, A0, A1, B0, B1, B2, B3)                                   \
    {                                                                       \
        const float* ga = Abase + (kk);                                     \
        A0 = *(const float4*)ga;                                            \
        A1 = *(const float4*)(ga + 4);                                      \
        const float* gb = Bbase + (long)(kk) * 128;                         \
        B0 = *(const float4*)gb;                                            \
        B1 = *(const float4*)(gb + 4);                                      \
        B2 = *(const float4*)(gb + 128);                                    \
        B3 = *(const float4*)(gb + 132);                                    \
    }

#define STAGE(A0, A1, B0, B1, B2, B3)                                       \
    {                                                                       \
        bf16x8 p;                                                           \
        p[0] = tob(A0.x); p[1] = tob(A0.y); p[2] = tob(A0.z); p[3] = tob(A0.w); \
        p[4] = tob(A1.x); p[5] = tob(A1.y); p[6] = tob(A1.z); p[7] = tob(A1.w); \
        *(bf16x8*)&As[ar][SWZ(ar, akp)] = p;                                \
        float va[8] = {B0.x, B0.y, B0.z, B0.w, B1.x, B1.y, B1.z, B1.w};     \
        float vb[8] = {B2.x, B2.y, B2.z, B2.w, B3.x, B3.y, B3.z, B3.w};     \
        _Pragma("unroll")                                                   \
        for (int j = 0; j < 8; ++j) {                                       \
            BPack q; q.h[0] = tob(va[j]); q.h[1] = tob(vb[j]);              \
            *(unsigned int*)&Bs[bd + j][SWZ(bd + j, bk)] = q.u;             \
        }                                                                   \
    }

#define MFMA_STEP                                                           \
    {                                                                       \
        const int rA = wm + lr;                                             \
        bf16x8 af0 = *(const bf16x8*)&As[rA][SWZ(rA, kb * 8)];              \
        bf16x8 af1 = *(const bf16x8*)&As[rA][SWZ(rA, kb * 8 + 32)];         \
        _Pragma("unroll")                                                   \
        for (int c = 0; c < 4; ++c) {                                       \
            const int rB = wn + c * 16 + lr;                                \
            bf16x8 b0 = *(const bf16x8*)&Bs[rB][SWZ(rB, kb * 8)];           \
            acc[c] = __builtin_amdgcn_mfma_f32_16x16x32_bf16(af0, b0, acc[c], 0, 0, 0); \
        }                                                                   \
        _Pragma("unroll")                                                   \
        for (int c = 0; c < 4; ++c) {                                       \
            const int rB = wn + c * 16 + lr;                                \
            bf16x8 b1 = *(const bf16x8*)&Bs[rB][SWZ(rB, kb * 8 + 32)];      \
            acc[c] = __builtin_amdgcn_mfma_f32_16x16x32_bf16(af1, b1, acc[c], 0, 0, 0); \
        }                                                                   \
    }

    GLOAD(kbeg, xa0, xa1, xb0, xb1, xb2, xb3);
    GLOAD(kbeg + 64, ya0, ya1, yb0, yb1, yb2, yb3);

    for (int kk = kbeg; kk < kend; kk += 128) {
        STAGE(xa0, xa1, xb0, xb1, xb2, xb3);
        __syncthreads();
        if (kk + 128 < kend) GLOAD(kk + 128, xa0, xa1, xb0, xb1, xb2, xb3);
        MFMA_STEP;
        __syncthreads();
        STAGE(ya0, ya1, yb0, yb1, yb2, yb3);
        __syncthreads();
        if (kk + 192 < kend) GLOAD(kk + 192, ya0, ya1, yb0, yb1, yb2, yb3);
        MFMA_STEP;
        __syncthreads();
    }
#undef GLOAD
#undef STAGE
#undef MFMA_STEP

    float* Cp = P + (long)(ksi * 4 + b) * 524288;
    const int rb = m0 + wm + kb * 4;
#pragma unroll
    for (int c = 0; c < 4; ++c) {
        const int col = wn + c * 16 + lr;
#pragma unroll
        for (int i = 0; i < 4; ++i)
            Cp[(long)(rb + i) * 128 + col] = acc[c][i];
    }
}

// ---------------------------------------------------------------------------
template <int KS>
static void run_all(const float* incident, const float* degree_v, const float* degree_e,
                    const float* x, const int* e_masks, const float* mlp_W,
                    const float* mlp_b, const float* theta, const float* epsp,
                    const float* bng, const float* bnb, const float* bnm,
                    const float* bnv, float* out, float* ws, hipStream_t stream) {
    float* xw  = ws;                  // 2M floats
    float* hxw = ws + 2097152;        // 2M
    float* t1  = ws + 4194304;        // 2M (reused as t3)
    float* Pd  = ws + 6291456;        // KS*2M
    float* tail = Pd + (long)KS * 2097152;
    u64* rowmask = (u64*)tail;            // 1M u64
    u64* colmask = rowmask + 1048576;     // 1M u64
    float* xt  = (float*)(colmask + 1048576);
    float* hxt = xt + 16384;
    float* att = hxt + 16384;

    mlp_k<<<512, 256, 0, stream>>>(x, mlp_W, mlp_b, theta, xw, xt);
    bmask_k<<<dim3(1024, 4), 256, 0, stream>>>(incident, rowmask);
    btrans_k<<<dim3(64, 64, 4), 64, 0, stream>>>(rowmask, colmask);

    const dim3 gG(1024, 4);
    // G1: hxw = Ht @ xw  (+ hxt = Ht @ xt)
    gather_k<1, false, false, true, false><<<gG, 256, 0, stream>>>(
        colmask, xw, nullptr, nullptr, xt, nullptr,
        nullptr, nullptr, nullptr, nullptr, hxw, hxt);
    softmax_k<<<4, 1024, 0, stream>>>(hxt, e_masks, att);
    // G2: t1 = incident @ (attn * hxw)
    gather_k<1, true, false, false, false><<<gG, 256, 0, stream>>>(
        rowmask, hxw, nullptr, att, nullptr, nullptr,
        nullptr, nullptr, nullptr, nullptr, t1, nullptr);
    // G3: Pd = degree_v @ t1   (split-K partials)
    gemm_dense<KS><<<dim3(64, KS, 4), 512, 0, stream>>>(degree_v, t1, Pd);
    // G4: t3(=t1) = Ht @ sum(Pd)
    gather_k<KS, false, false, false, false><<<gG, 256, 0, stream>>>(
        colmask, Pd, nullptr, nullptr, nullptr, nullptr,
        nullptr, nullptr, nullptr, nullptr, t1, nullptr);
    // G5: Pd = degree_e @ t3
    gemm_dense<KS><<<dim3(64, KS, 4), 512, 0, stream>>>(degree_e, t1, Pd);
    // G6: out = BN(leaky(incident @ (sum(Pd) + eps*hxw)))
    gather_k<KS, false, true, false, true><<<gG, 256, 0, stream>>>(
        rowmask, Pd, hxw, nullptr, nullptr, epsp,
        bng, bnb, bnm, bnv, out, nullptr);
}

extern "C" void kernel_launch(void* const* d_in, const int* in_sizes, int n_in,
                              void* d_out, int out_size, void* d_ws, size_t ws_size,
                              hipStream_t stream) {
    const float* incident = (const float*)d_in[0];
    const float* degree_v = (const float*)d_in[1];
    const float* degree_e = (const float*)d_in[2];
    const float* x        = (const float*)d_in[3];
    const int*   e_masks  = (const int*)d_in[4];
    const float* mlp_W    = (const float*)d_in[5];
    const float* mlp_b    = (const float*)d_in[6];
    const float* theta    = (const float*)d_in[7];
    const float* epsp     = (const float*)d_in[8];
    const float* bng      = (const float*)d_in[9];
    const float* bnb      = (const float*)d_in[10];
    const float* bnm      = (const float*)d_in[11];
    const float* bnv      = (const float*)d_in[12];
    float* out = (float*)d_out;
    float* ws = (float*)d_ws;

    // KS=2 needs 14,729,216 floats = 58,916,864 B (proven available in R2).
    if (ws_size >= 58916864ull)
        run_all<2>(incident, degree_v, degree_e, x, e_masks, mlp_W, mlp_b, theta,
                   epsp, bng, bnb, bnm, bnv, out, ws, stream);
    else
        run_all<1>(incident, degree_v, degree_e, x, e_masks, mlp_W, mlp_b, theta,
                   epsp, bng, bnb, bnm, bnv, out, ws, stream);
}